// Round 5
// baseline (312.978 us; speedup 1.0000x reference)
//
#include <hip/hip_runtime.h>

// pred, target: [32,1,1024,1024] f32 -> scalar f32 = mean((softplus(p)-p*t)*w),
// w = 0.1 on 5x5 morphological gradient of binarized target, gated on
// cond = (t.max()==1 && t.min()==0).
//
// R3c: barrier-free wave-autonomous streaming. Compile fix: use __expf/__logf
// (known-good in R1/R2; lower to v_exp_f32/v_log_f32).
// Each wave owns an 8-row band (full width). Rolling 5-row ring of ballot
// bit-words in registers (lane l holds word l&15; interleaved layout:
// col = 256*it + 4*lane + m <-> word 4*it+m, bit lane). Vertical OR/AND in
// registers; horizontal +-2 via shfl with wrap logic (verified in R2);
// t/e words broadcast via v_readlane. No __syncthreads in streaming path.
// 1024 blocks x 256 = 4096 waves, 16 waves/CU, deep ILP.

#define IMG  1024
#define RPW  8                      // rows per wave
#define NTOT 33554432.0

typedef unsigned long long u64;

__device__ __forceinline__ u64 shfl64(u64 v, int src) {
    unsigned lo = (unsigned)__shfl((int)(unsigned)(v & 0xffffffffULL), src, 64);
    unsigned hi = (unsigned)__shfl((int)(unsigned)(v >> 32), src, 64);
    return ((u64)hi << 32) | lo;
}
// broadcast word from a compile-time lane (readlane -> SGPR, no LDS pipe)
__device__ __forceinline__ u64 bcast64(u64 v, int srcImm) {
    unsigned lo = (unsigned)__builtin_amdgcn_readlane((int)(unsigned)(v & 0xffffffffULL), srcImm);
    unsigned hi = (unsigned)__builtin_amdgcn_readlane((int)(unsigned)(v >> 32), srcImm);
    return ((u64)hi << 32) | lo;
}

__device__ __forceinline__ unsigned encf(float f) {
    unsigned u = __float_as_uint(f);
    return (u & 0x80000000u) ? ~u : (u | 0x80000000u);
}
__device__ __forceinline__ float decf(unsigned e) {
    unsigned u = (e & 0x80000000u) ? (e & 0x7fffffffu) : ~e;
    return __uint_as_float(u);
}

__global__ void bbl_init(double* dws, unsigned* uws) {
    if (threadIdx.x == 0) {
        dws[0] = 0.0; dws[1] = 0.0;
        uws[0] = 0xFFFFFFFFu;   // running min (encoded)
        uws[1] = 0u;            // running max (encoded)
    }
}

__global__ __launch_bounds__(256) void bbl_main(
        const float* __restrict__ pred,
        const float* __restrict__ target,
        double* __restrict__ dws, unsigned* __restrict__ uws) {
    __shared__ float    redS1[4], redSe[4];
    __shared__ unsigned redMn[4], redMx[4];

    const int tid  = threadIdx.x;
    const int lane = tid & 63;
    const int wid  = tid >> 6;
    const int gw   = blockIdx.x * 4 + wid;        // 0..4095
    const int img  = gw >> 7;                     // 128 bands / image
    const int r0   = (gw & 127) * RPW;
    const size_t base = (size_t)img * IMG * IMG;
    const float* tbase = target + base;
    const float* pbase = pred + base;

    const int w = lane & 15;                      // my bit-word index
    const int k = w & 3;

    float vmin = 3.4e38f, vmax = -3.4e38f;
    float s1 = 0.f, se = 0.f;

    // load one target row -> my bit-word (interleaved layout); mm gates the
    // exact min/max accumulation to rows owned by this wave (halo rows are
    // owned by the neighbor band; clamped duplicates get mm=false too).
    auto loadrow = [&](int gr, bool mm) -> u64 {
        const float4* rp = (const float4*)(tbase + (size_t)gr * IMG);
        u64 myw = 0ULL;
        #pragma unroll
        for (int it = 0; it < 4; ++it) {
            float4 v = rp[it * 64 + lane];
            if (mm) {   // wave-uniform branch
                vmin = fminf(vmin, fminf(fminf(v.x, v.y), fminf(v.z, v.w)));
                vmax = fmaxf(vmax, fmaxf(fmaxf(v.x, v.y), fmaxf(v.z, v.w)));
            }
            u64 b0 = __ballot(v.x > 0.5f);
            u64 b1 = __ballot(v.y > 0.5f);
            u64 b2 = __ballot(v.z > 0.5f);
            u64 b3 = __ballot(v.w > 0.5f);
            u64 bw = (k == 0) ? b0 : (k == 1) ? b1 : (k == 2) ? b2 : b3;
            if ((w >> 2) == it) myw = bw;
        }
        return myw;
    };

    // ring: rows clamp(r-2) .. clamp(r+2); OR/AND idempotent under clamping,
    // matching the -inf/+inf reduce_window SAME padding.
    u64 q0 = loadrow(max(r0 - 2, 0), false);
    u64 q1 = loadrow(max(r0 - 1, 0), false);
    u64 q2 = loadrow(r0, true);
    u64 q3 = loadrow(r0 + 1, true);

    for (int r = r0; r < r0 + RPW; ++r) {
        const int nr = min(r + 2, IMG - 1);
        u64 q4 = loadrow(nr, r + 2 <= r0 + RPW - 1);

        // issue pred loads early (independent of the bit chain)
        const float4* pp = (const float4*)(pbase + (size_t)r * IMG);
        float4 p0 = pp[0 * 64 + lane];
        float4 p1 = pp[1 * 64 + lane];
        float4 p2 = pp[2 * 64 + lane];
        float4 p3 = pp[3 * 64 + lane];

        u64 vd = q0 | q1 | q2 | q3 | q4;          // vertical dilate
        u64 ve = q0 & q1 & q2 & q3 & q4;          // vertical erode
        u64 ct = q2;                              // center row raw bits

        // horizontal +-2 in interleaved bit domain
        u64 hd = vd, he = ve;
        #pragma unroll
        for (int di = 0; di < 4; ++di) {
            const int d = (di < 2) ? di - 2 : di - 1;  // -2,-1,1,2
            int wp = w + d;
            bool inp = (wp >= 0) && (wp < 16);
            u64 ad = shfl64(vd, wp & 15);
            u64 ae = shfl64(ve, wp & 15);
            ad = inp ? ad : 0ULL;                 // OOB col: dilate identity
            ae = inp ? ae : ~0ULL;                // OOB col: erode identity
            int ws2 = wp + ((d > 0) ? -4 : 4);
            u64 bd = shfl64(vd, ws2 & 15);
            u64 be = shfl64(ve, ws2 & 15);
            int kp = k + d;
            u64 rd, re;
            if (d > 0) {
                u64 wd = (bd >> 1) | (ad << 63);
                u64 we = (be >> 1) | (ae << 63);
                rd = (kp <= 3) ? ad : wd;
                re = (kp <= 3) ? ae : we;
            } else {
                u64 wd = (bd << 1) | (ad >> 63);
                u64 we = (be << 1) | (ae >> 63);
                rd = (kp >= 0) ? ad : wd;
                re = (kp >= 0) ? ae : we;
            }
            hd |= rd; he &= re;
        }
        u64 em = hd & ~he;                        // edge bits for my word

        // consume pred with broadcast bit-words
        #pragma unroll
        for (int it = 0; it < 4; ++it) {
            float4 p = (it == 0) ? p0 : (it == 1) ? p1 : (it == 2) ? p2 : p3;
            #pragma unroll
            for (int m = 0; m < 4; ++m) {
                u64 ew = bcast64(em, it * 4 + m);
                u64 tw = bcast64(ct, it * 4 + m);
                float x = (m == 0) ? p.x : (m == 1) ? p.y : (m == 2) ? p.z : p.w;
                unsigned tb = (unsigned)(tw >> lane) & 1u;
                unsigned eb = (unsigned)(ew >> lane) & 1u;
                float xt = tb ? x : 0.f;
                // stable softplus: max(x,0) + log(1+exp(-|x|))
                float sp = fmaxf(x, 0.f) + __logf(1.f + __expf(-fabsf(x)));
                float loss = sp - xt;
                s1 += loss;
                se += eb ? loss : 0.f;
            }
        }

        q0 = q1; q1 = q2; q2 = q3; q3 = q4;       // advance ring
    }

    // wave reduce
    for (int off = 32; off > 0; off >>= 1) {
        s1   += __shfl_down(s1, off);
        se   += __shfl_down(se, off);
        vmin  = fminf(vmin, __shfl_down(vmin, off));
        vmax  = fmaxf(vmax, __shfl_down(vmax, off));
    }
    if (lane == 0) {
        redS1[wid] = s1; redSe[wid] = se;
        redMn[wid] = encf(vmin); redMx[wid] = encf(vmax);
    }
    __syncthreads();
    if (tid == 0) {
        float S1 = 0.f, Se = 0.f; unsigned mn = 0xFFFFFFFFu, mx = 0u;
        #pragma unroll
        for (int i = 0; i < 4; ++i) {
            S1 += redS1[i]; Se += redSe[i];
            mn = min(mn, redMn[i]); mx = max(mx, redMx[i]);
        }
        atomicAdd(&dws[0], (double)S1);
        atomicAdd(&dws[1], (double)Se);
        atomicMin(&uws[0], mn);
        atomicMax(&uws[1], mx);
    }
}

__global__ void bbl_fin(const double* __restrict__ dws,
                        const unsigned* __restrict__ uws,
                        float* __restrict__ out) {
    if (threadIdx.x == 0) {
        float fmin = decf(uws[0]);
        float fmax = decf(uws[1]);
        bool cond = (fmax == 1.0f) && (fmin == 0.0f);
        double s = cond ? (dws[0] - 0.9 * dws[1]) : dws[0];
        out[0] = (float)(s / NTOT);
    }
}

extern "C" void kernel_launch(void* const* d_in, const int* in_sizes, int n_in,
                              void* d_out, int out_size, void* d_ws, size_t ws_size,
                              hipStream_t stream) {
    const float* pred   = (const float*)d_in[0];
    const float* target = (const float*)d_in[1];
    double*   dws = (double*)d_ws;
    unsigned* uws = (unsigned*)(dws + 2);
    float*    out = (float*)d_out;

    hipLaunchKernelGGL(bbl_init, dim3(1), dim3(64), 0, stream, dws, uws);
    hipLaunchKernelGGL(bbl_main, dim3(1024), dim3(256), 0, stream,
                       pred, target, dws, uws);
    hipLaunchKernelGGL(bbl_fin, dim3(1), dim3(64), 0, stream, dws, uws, out);
}